// Round 6
// baseline (418.305 us; speedup 1.0000x reference)
//
#include <hip/hip_runtime.h>
#include <hip/hip_fp16.h>

#define NSTEPS 30
#define DIM 192
static constexpr long DHW = (long)DIM * DIM * DIM;
static constexpr int PTS_PER_WAVE = 21;   // 3 lanes per point
static constexpr int NBINS = 12 * 12 * 12;  // 16^3-voxel supercells

// Unrolled cofactor 4x4 inverse in double — registers only, no scratch.
__global__ void invert4x4_kernel(const float* __restrict__ aff,
                                 float* __restrict__ out, int B) {
    int b = blockIdx.x * blockDim.x + threadIdx.x;
    if (b >= B) return;
    double a[16];
#pragma unroll
    for (int i = 0; i < 16; i++) a[i] = (double)aff[b * 16 + i];
    double s0 = a[0]*a[5]  - a[4]*a[1];
    double s1 = a[0]*a[6]  - a[4]*a[2];
    double s2 = a[0]*a[7]  - a[4]*a[3];
    double s3 = a[1]*a[6]  - a[5]*a[2];
    double s4 = a[1]*a[7]  - a[5]*a[3];
    double s5 = a[2]*a[7]  - a[6]*a[3];
    double c5 = a[10]*a[15] - a[14]*a[11];
    double c4 = a[9]*a[15]  - a[13]*a[11];
    double c3 = a[9]*a[14]  - a[13]*a[10];
    double c2 = a[8]*a[15]  - a[12]*a[11];
    double c1 = a[8]*a[14]  - a[12]*a[10];
    double c0 = a[8]*a[13]  - a[12]*a[9];
    double det = s0*c5 - s1*c4 + s2*c3 + s3*c2 - s4*c1 + s5*c0;
    double inv = 1.0 / det;
    double o[16];
    o[0]  = ( a[5]*c5 - a[6]*c4 + a[7]*c3) * inv;
    o[1]  = (-a[1]*c5 + a[2]*c4 - a[3]*c3) * inv;
    o[2]  = ( a[13]*s5 - a[14]*s4 + a[15]*s3) * inv;
    o[3]  = (-a[9]*s5 + a[10]*s4 - a[11]*s3) * inv;
    o[4]  = (-a[4]*c5 + a[6]*c2 - a[7]*c1) * inv;
    o[5]  = ( a[0]*c5 - a[2]*c2 + a[3]*c1) * inv;
    o[6]  = (-a[12]*s5 + a[14]*s2 - a[15]*s1) * inv;
    o[7]  = ( a[8]*s5 - a[10]*s2 + a[11]*s1) * inv;
    o[8]  = ( a[4]*c4 - a[5]*c2 + a[7]*c0) * inv;
    o[9]  = (-a[0]*c4 + a[1]*c2 - a[3]*c0) * inv;
    o[10] = ( a[12]*s4 - a[13]*s2 + a[15]*s0) * inv;
    o[11] = (-a[8]*s4 + a[9]*s2 - a[11]*s0) * inv;
    o[12] = (-a[4]*c3 + a[5]*c1 - a[6]*c0) * inv;
    o[13] = ( a[0]*c3 - a[1]*c1 + a[2]*c0) * inv;
    o[14] = (-a[12]*s3 + a[13]*s1 - a[14]*s0) * inv;
    o[15] = ( a[8]*s3 - a[9]*s1 + a[10]*s0) * inv;
#pragma unroll
    for (int i = 0; i < 16; i++) out[b * 16 + i] = (float)o[i];
}

// Repack flow (B,3,D,H,W) f32 -> (B,D,H,W,4) fp16, 4 voxels/thread vectorized.
__global__ __launch_bounds__(256) void repack4_kernel(const float* __restrict__ flow,
                                                      __half* __restrict__ packed) {
    long q = (long)blockIdx.x * blockDim.x + threadIdx.x;   // quad index
    int b = blockIdx.y;
    long v0 = q * 4;
    if (v0 >= DHW) return;
    const float* F = flow + (size_t)b * 3 * DHW;
    float4 f0 = *reinterpret_cast<const float4*>(F + v0);
    float4 f1 = *reinterpret_cast<const float4*>(F + v0 + DHW);
    float4 f2 = *reinterpret_cast<const float4*>(F + v0 + 2 * DHW);
    union { __half2 h[2]; int2 i2; } u;
    int4 o0, o1;
    u.h[0] = __floats2half2_rn(f0.x, f1.x); u.h[1] = __floats2half2_rn(f2.x, 0.f);
    o0.x = u.i2.x; o0.y = u.i2.y;
    u.h[0] = __floats2half2_rn(f0.y, f1.y); u.h[1] = __floats2half2_rn(f2.y, 0.f);
    o0.z = u.i2.x; o0.w = u.i2.y;
    u.h[0] = __floats2half2_rn(f0.z, f1.z); u.h[1] = __floats2half2_rn(f2.z, 0.f);
    o1.x = u.i2.x; o1.y = u.i2.y;
    u.h[0] = __floats2half2_rn(f0.w, f1.w); u.h[1] = __floats2half2_rn(f2.w, 0.f);
    o1.z = u.i2.x; o1.w = u.i2.y;
    int4* out = reinterpret_cast<int4*>(packed) + (((size_t)b * DHW + v0) >> 1);
    out[0] = o0;
    out[1] = o1;
}

// Spatial binning: key = 16^3 supercell of initial (post-affine, clamped) position.
__global__ __launch_bounds__(256) void bin_count_kernel(
    const float* __restrict__ verts, const float* __restrict__ affine,
    unsigned* __restrict__ hist, unsigned short* __restrict__ keys, int N, int B) {
    int i = blockIdx.x * blockDim.x + threadIdx.x;
    if (i >= B * N) return;
    int b = i / N;
    const float* A = affine + b * 16;
    const float* v = verts + (size_t)i * 3;
    float vx = v[0], vy = v[1], vz = v[2];
    float x = A[0] * vx + A[1] * vy + A[2]  * vz + A[3];
    float y = A[4] * vx + A[5] * vy + A[6]  * vz + A[7];
    float z = A[8] * vx + A[9] * vy + A[10] * vz + A[11];
    int d0 = (int)floorf(fminf(fmaxf(x, 0.0f), (float)(DIM - 1)));
    int h0 = (int)floorf(fminf(fmaxf(y, 0.0f), (float)(DIM - 1)));
    int w0 = (int)floorf(fminf(fmaxf(z, 0.0f), (float)(DIM - 1)));
    unsigned key = ((unsigned)(d0 >> 4) * 12 + (unsigned)(h0 >> 4)) * 12
                 + (unsigned)(w0 >> 4);
    keys[i] = (unsigned short)key;
    atomicAdd(&hist[key], 1u);
}

// Exclusive scan of NBINS=1728 bins, single 256-thread block.
__global__ __launch_bounds__(256) void scan_bins_kernel(
    const unsigned* __restrict__ hist, unsigned* __restrict__ offs) {
    __shared__ unsigned lsum[256];
    int t = threadIdx.x;
    unsigned loc[7];
    unsigned s = 0;
#pragma unroll
    for (int j = 0; j < 7; j++) {
        int i = t * 7 + j;
        unsigned v = (i < NBINS) ? hist[i] : 0u;
        loc[j] = s;
        s += v;
    }
    lsum[t] = s;
    __syncthreads();
    for (int off = 1; off < 256; off <<= 1) {
        unsigned v = (t >= off) ? lsum[t - off] : 0u;
        __syncthreads();
        lsum[t] += v;
        __syncthreads();
    }
    unsigned base = (t > 0) ? lsum[t - 1] : 0u;
#pragma unroll
    for (int j = 0; j < 7; j++) {
        int i = t * 7 + j;
        if (i < NBINS) offs[i] = base + loc[j];
    }
}

__global__ __launch_bounds__(256) void scatter_kernel(
    const unsigned short* __restrict__ keys, unsigned* __restrict__ offs,
    unsigned* __restrict__ perm, int total) {
    int i = blockIdx.x * blockDim.x + threadIdx.x;
    if (i >= total) return;
    unsigned pos = atomicAdd(&offs[keys[i]], 1u);
    perm[pos] = (unsigned)i;
}

static __device__ __forceinline__ float2 h2f(unsigned u) {
    return __half22float2(__builtin_bit_cast(__half2, u));
}

// 3 lanes per point, sorted order via perm, XCD-swizzled blocks.
__global__ __launch_bounds__(256) void deform_sorted_kernel(
    const float* __restrict__ verts,
    const float* __restrict__ affine,
    const __half* __restrict__ packed,
    const float* __restrict__ invaff,
    const unsigned* __restrict__ perm,
    float* __restrict__ out_pred,
    float* __restrict__ out_flow,
    int N, int B, int nblk8) {
    // swizzle so consecutive sorted blocks share an XCD's L2 (HW: blk % 8 -> XCD)
    int bi = blockIdx.x;
    int lblk = (bi & 7) * (nblk8 >> 3) + (bi >> 3);
    int lane = threadIdx.x & 63;
    int wib  = threadIdx.x >> 6;
    long gwave = (long)lblk * 4 + wib;

    int piw = lane / 3;
    if (piw > PTS_PER_WAVE - 1) piw = PTS_PER_WAVE - 1;
    int ch = lane - piw * 3;
    if (ch > 2) ch = 2;

    long slot = gwave * PTS_PER_WAVE + piw;
    long total = (long)B * N;
    bool valid = (lane < 63) && (slot < total);
    long sc = valid ? slot : total - 1;
    long ptc = (long)perm[sc];
    int b = (int)(ptc / N);
    int n = (int)(ptc - (long)b * N);

    const float* A = affine + b * 16;
    const float* v = verts + (size_t)ptc * 3;
    float vx = v[0], vy = v[1], vz = v[2];
    float x = A[0] * vx + A[1] * vy + A[2]  * vz + A[3];
    float y = A[4] * vx + A[5] * vy + A[6]  * vz + A[7];
    float z = A[8] * vx + A[9] * vy + A[10] * vz + A[11];
    float p0 = (ch == 0) ? x : (ch == 1) ? y : z;

    // own-channel base into the interleaved volume (units: halves)
    const __half* Pb = packed + ((size_t)b * DHW) * 4 + ch;
    const float scale = (float)(1.0 / NSTEPS);

    float cc[8];
    int key = -1;
    int bl = piw * 3;

    for (int s = 0; s < NSTEPS; s++) {
        float pd = fminf(fmaxf(x, 0.0f), (float)(DIM - 1));
        float ph = fminf(fmaxf(y, 0.0f), (float)(DIM - 1));
        float pw = fminf(fmaxf(z, 0.0f), (float)(DIM - 1));
        float fd0 = floorf(pd), fh0 = floorf(ph), fw0 = floorf(pw);
        int d0 = (int)fd0, h0 = (int)fh0, w0 = (int)fw0;
        float fd = pd - fd0, fh = ph - fh0, fw = pw - fw0;

        int k = (d0 * DIM + h0) * DIM + w0;
        if (k != key) {
            key = k;
            int d1 = min(d0 + 1, DIM - 1);
            int h1 = min(h0 + 1, DIM - 1);
            int w1 = min(w0 + 1, DIM - 1);
            size_t r00 = (size_t)((d0 * DIM + h0) * DIM) * 4;
            size_t r01 = (size_t)((d0 * DIM + h1) * DIM) * 4;
            size_t r10 = (size_t)((d1 * DIM + h0) * DIM) * 4;
            size_t r11 = (size_t)((d1 * DIM + h1) * DIM) * 4;
            size_t o0 = (size_t)w0 * 4, o1 = (size_t)w1 * 4;
            cc[0] = __half2float(Pb[r00 + o0]) * scale;
            cc[1] = __half2float(Pb[r00 + o1]) * scale;
            cc[2] = __half2float(Pb[r01 + o0]) * scale;
            cc[3] = __half2float(Pb[r01 + o1]) * scale;
            cc[4] = __half2float(Pb[r10 + o0]) * scale;
            cc[5] = __half2float(Pb[r10 + o1]) * scale;
            cc[6] = __half2float(Pb[r11 + o0]) * scale;
            cc[7] = __half2float(Pb[r11 + o1]) * scale;
        }

        float omfw = 1.0f - fw, omfh = 1.0f - fh, omfd = 1.0f - fd;
        float c00 = cc[0] * omfw + cc[1] * fw;
        float c01 = cc[2] * omfw + cc[3] * fw;
        float c10 = cc[4] * omfw + cc[5] * fw;
        float c11 = cc[6] * omfw + cc[7] * fw;
        float c0 = c00 * omfh + c01 * fh;
        float c1 = c10 * omfh + c11 * fh;
        float val = c0 * omfd + c1 * fd;

        float v0 = __shfl(val, bl,     64);
        float v1 = __shfl(val, bl + 1, 64);
        float v2 = __shfl(val, bl + 2, 64);
        x += v0; y += v1; z += v2;
    }

    if (valid) {
        float posc = (ch == 0) ? x : (ch == 1) ? y : z;
        float fint = posc - p0;
        const float* Ai = invaff + b * 16 + ch * 4;
        float o = Ai[0] * x + Ai[1] * y + Ai[2] * z + Ai[3];
        out_pred[(size_t)ptc * 3 + ch] = o;                        // (B,N,3)
        out_flow[(size_t)b * 3 * N + (size_t)ch * N + n] = fint;   // (B,3,N)
    }
}

// Fallback: f32 direct-gather (3 lanes/point) if ws can't hold the packed volume.
__global__ __launch_bounds__(256) void deform_kernel(
    const float* __restrict__ verts,
    const float* __restrict__ affine,
    const float* __restrict__ flow,
    const float* __restrict__ invaff,
    float* __restrict__ out_pred,
    float* __restrict__ out_flow,
    int N, int B) {
    int lane = threadIdx.x & 63;
    int wib  = threadIdx.x >> 6;
    long gwave = (long)blockIdx.x * (blockDim.x >> 6) + wib;
    int piw = lane / 3;
    if (piw > PTS_PER_WAVE - 1) piw = PTS_PER_WAVE - 1;
    int ch = lane - piw * 3;
    if (ch > 2) ch = 2;
    long pt = gwave * PTS_PER_WAVE + piw;
    bool valid = (lane < 63) && (pt < (long)B * N);
    long ptc = valid ? pt : ((long)B * N - 1);
    int b = (int)(ptc / N);
    int n = (int)(ptc - (long)b * N);
    const float* A = affine + b * 16;
    const float* v = verts + (size_t)ptc * 3;
    float vx = v[0], vy = v[1], vz = v[2];
    float x = A[0] * vx + A[1] * vy + A[2]  * vz + A[3];
    float y = A[4] * vx + A[5] * vy + A[6]  * vz + A[7];
    float z = A[8] * vx + A[9] * vy + A[10] * vz + A[11];
    float p0 = (ch == 0) ? x : (ch == 1) ? y : z;
    const float* Fc = flow + ((size_t)b * 3 + ch) * (size_t)DHW;
    const float scale = (float)(1.0 / NSTEPS);
    float cc[8];
    int key = -1;
    int bl = piw * 3;
    for (int s = 0; s < NSTEPS; s++) {
        float pd = fminf(fmaxf(x, 0.0f), (float)(DIM - 1));
        float ph = fminf(fmaxf(y, 0.0f), (float)(DIM - 1));
        float pw = fminf(fmaxf(z, 0.0f), (float)(DIM - 1));
        float fd0 = floorf(pd), fh0 = floorf(ph), fw0 = floorf(pw);
        int d0 = (int)fd0, h0 = (int)fh0, w0 = (int)fw0;
        float fd = pd - fd0, fh = ph - fh0, fw = pw - fw0;
        int k = (d0 * DIM + h0) * DIM + w0;
        if (k != key) {
            key = k;
            int d1 = min(d0 + 1, DIM - 1);
            int h1 = min(h0 + 1, DIM - 1);
            int w1 = min(w0 + 1, DIM - 1);
            int r00 = (d0 * DIM + h0) * DIM;
            int r01 = (d0 * DIM + h1) * DIM;
            int r10 = (d1 * DIM + h0) * DIM;
            int r11 = (d1 * DIM + h1) * DIM;
            cc[0] = Fc[r00 + w0] * scale;
            cc[1] = Fc[r00 + w1] * scale;
            cc[2] = Fc[r01 + w0] * scale;
            cc[3] = Fc[r01 + w1] * scale;
            cc[4] = Fc[r10 + w0] * scale;
            cc[5] = Fc[r10 + w1] * scale;
            cc[6] = Fc[r11 + w0] * scale;
            cc[7] = Fc[r11 + w1] * scale;
        }
        float omfw = 1.0f - fw, omfh = 1.0f - fh, omfd = 1.0f - fd;
        float c00 = cc[0] * omfw + cc[1] * fw;
        float c01 = cc[2] * omfw + cc[3] * fw;
        float c10 = cc[4] * omfw + cc[5] * fw;
        float c11 = cc[6] * omfw + cc[7] * fw;
        float c0 = c00 * omfh + c01 * fh;
        float c1 = c10 * omfh + c11 * fh;
        float val = c0 * omfd + c1 * fd;
        float v0 = __shfl(val, bl,     64);
        float v1 = __shfl(val, bl + 1, 64);
        float v2 = __shfl(val, bl + 2, 64);
        x += v0; y += v1; z += v2;
    }
    if (valid) {
        float posc = (ch == 0) ? x : (ch == 1) ? y : z;
        float fint = posc - p0;
        const float* Ai = invaff + b * 16 + ch * 4;
        float o = Ai[0] * x + Ai[1] * y + Ai[2] * z + Ai[3];
        out_pred[(size_t)ptc * 3 + ch] = o;
        out_flow[(size_t)b * 3 * N + (size_t)ch * N + n] = fint;
    }
}

extern "C" void kernel_launch(void* const* d_in, const int* in_sizes, int n_in,
                              void* d_out, int out_size, void* d_ws, size_t ws_size,
                              hipStream_t stream) {
    const float* verts  = (const float*)d_in[0];
    const float* affine = (const float*)d_in[1];
    const float* flow   = (const float*)d_in[2];

    int B = in_sizes[1] / 16;          // affine is B*4*4
    int N = in_sizes[0] / (3 * B);     // verts is B*N*3
    long total = (long)B * N;

    float* out_pred = (float*)d_out;                      // (B,N,3)
    float* out_flow = out_pred + (size_t)B * N * 3;       // (B,3,N)

    // ws layout
    size_t packed_bytes = (size_t)B * DHW * 4 * sizeof(__half);           // 113 MB
    size_t off_invaff = packed_bytes;
    size_t off_hist   = off_invaff + (size_t)B * 16 * sizeof(float);
    size_t off_offs   = off_hist + NBINS * sizeof(unsigned);
    size_t off_perm   = off_offs + NBINS * sizeof(unsigned);
    size_t off_keys   = off_perm + (size_t)total * sizeof(unsigned);
    size_t need = off_keys + (size_t)total * sizeof(unsigned short) + 256;
    bool use_packed = (ws_size >= need);

    if (use_packed) {
        char* ws = (char*)d_ws;
        __half* packed        = (__half*)ws;
        float* invaff         = (float*)(ws + off_invaff);
        unsigned* hist        = (unsigned*)(ws + off_hist);
        unsigned* offs        = (unsigned*)(ws + off_offs);
        unsigned* perm        = (unsigned*)(ws + off_perm);
        unsigned short* keys  = (unsigned short*)(ws + off_keys);

        hipLaunchKernelGGL(invert4x4_kernel, dim3(1), dim3(64), 0, stream,
                           affine, invaff, B);
        long quads = (DHW + 3) / 4;
        long vblocks = (quads + 255) / 256;
        hipLaunchKernelGGL(repack4_kernel, dim3((unsigned)vblocks, B), dim3(256), 0,
                           stream, flow, packed);
        hipMemsetAsync(hist, 0, NBINS * sizeof(unsigned), stream);
        int pblocks = (int)((total + 255) / 256);
        hipLaunchKernelGGL(bin_count_kernel, dim3(pblocks), dim3(256), 0, stream,
                           verts, affine, hist, keys, N, B);
        hipLaunchKernelGGL(scan_bins_kernel, dim3(1), dim3(256), 0, stream,
                           hist, offs);
        hipLaunchKernelGGL(scatter_kernel, dim3(pblocks), dim3(256), 0, stream,
                           keys, offs, perm, (int)total);

        long waves  = (total + PTS_PER_WAVE - 1) / PTS_PER_WAVE;
        long blocks = (waves + 3) / 4;          // 4 waves / 256-thr block
        long blocks8 = ((blocks + 7) / 8) * 8;  // pad for XCD swizzle
        hipLaunchKernelGGL(deform_sorted_kernel, dim3((unsigned)blocks8), dim3(256),
                           0, stream, verts, affine, packed, invaff, perm,
                           out_pred, out_flow, N, B, (int)blocks8);
    } else {
        float* invaff = (float*)d_ws;
        hipLaunchKernelGGL(invert4x4_kernel, dim3(1), dim3(64), 0, stream,
                           affine, invaff, B);
        long waves  = (total + PTS_PER_WAVE - 1) / PTS_PER_WAVE;
        long blocks = (waves + 3) / 4;
        hipLaunchKernelGGL(deform_kernel, dim3((unsigned)blocks), dim3(256), 0,
                           stream, verts, affine, flow, invaff,
                           out_pred, out_flow, N, B);
    }
}

// Round 7
// 366.046 us; speedup vs baseline: 1.1428x; 1.1428x over previous
//
#include <hip/hip_runtime.h>
#include <hip/hip_fp16.h>

#define NSTEPS 30
#define DIM 192
static constexpr long DHW = (long)DIM * DIM * DIM;
static constexpr int PTS_PER_WAVE = 21;   // fallback kernel only

// Unrolled cofactor 4x4 inverse in double — registers only, no scratch.
__global__ void invert4x4_kernel(const float* __restrict__ aff,
                                 float* __restrict__ out, int B) {
    int b = blockIdx.x * blockDim.x + threadIdx.x;
    if (b >= B) return;
    double a[16];
#pragma unroll
    for (int i = 0; i < 16; i++) a[i] = (double)aff[b * 16 + i];
    double s0 = a[0]*a[5]  - a[4]*a[1];
    double s1 = a[0]*a[6]  - a[4]*a[2];
    double s2 = a[0]*a[7]  - a[4]*a[3];
    double s3 = a[1]*a[6]  - a[5]*a[2];
    double s4 = a[1]*a[7]  - a[5]*a[3];
    double s5 = a[2]*a[7]  - a[6]*a[3];
    double c5 = a[10]*a[15] - a[14]*a[11];
    double c4 = a[9]*a[15]  - a[13]*a[11];
    double c3 = a[9]*a[14]  - a[13]*a[10];
    double c2 = a[8]*a[15]  - a[12]*a[11];
    double c1 = a[8]*a[14]  - a[12]*a[10];
    double c0 = a[8]*a[13]  - a[12]*a[9];
    double det = s0*c5 - s1*c4 + s2*c3 + s3*c2 - s4*c1 + s5*c0;
    double inv = 1.0 / det;
    double o[16];
    o[0]  = ( a[5]*c5 - a[6]*c4 + a[7]*c3) * inv;
    o[1]  = (-a[1]*c5 + a[2]*c4 - a[3]*c3) * inv;
    o[2]  = ( a[13]*s5 - a[14]*s4 + a[15]*s3) * inv;
    o[3]  = (-a[9]*s5 + a[10]*s4 - a[11]*s3) * inv;
    o[4]  = (-a[4]*c5 + a[6]*c2 - a[7]*c1) * inv;
    o[5]  = ( a[0]*c5 - a[2]*c2 + a[3]*c1) * inv;
    o[6]  = (-a[12]*s5 + a[14]*s2 - a[15]*s1) * inv;
    o[7]  = ( a[8]*s5 - a[10]*s2 + a[11]*s1) * inv;
    o[8]  = ( a[4]*c4 - a[5]*c2 + a[7]*c0) * inv;
    o[9]  = (-a[0]*c4 + a[1]*c2 - a[3]*c0) * inv;
    o[10] = ( a[12]*s4 - a[13]*s2 + a[15]*s0) * inv;
    o[11] = (-a[8]*s4 + a[9]*s2 - a[11]*s0) * inv;
    o[12] = (-a[4]*c3 + a[5]*c1 - a[6]*c0) * inv;
    o[13] = ( a[0]*c3 - a[1]*c1 + a[2]*c0) * inv;
    o[14] = (-a[12]*s3 + a[13]*s1 - a[14]*s0) * inv;
    o[15] = ( a[8]*s3 - a[9]*s1 + a[10]*s0) * inv;
#pragma unroll
    for (int i = 0; i < 16; i++) out[b * 16 + i] = (float)o[i];
}

// Repack flow (B,3,D,H,W) f32 -> (B,D,H,W,4) fp16 PRE-SCALED by 1/NSTEPS.
__global__ __launch_bounds__(256) void repack4_kernel(const float* __restrict__ flow,
                                                      __half* __restrict__ packed) {
    long q = (long)blockIdx.x * blockDim.x + threadIdx.x;   // quad index
    int b = blockIdx.y;
    long v0 = q * 4;
    if (v0 >= DHW) return;
    const float s = (float)(1.0 / NSTEPS);
    const float* F = flow + (size_t)b * 3 * DHW;
    float4 f0 = *reinterpret_cast<const float4*>(F + v0);
    float4 f1 = *reinterpret_cast<const float4*>(F + v0 + DHW);
    float4 f2 = *reinterpret_cast<const float4*>(F + v0 + 2 * DHW);
    union { __half2 h[2]; int2 i2; } u;
    int4 o0, o1;
    u.h[0] = __floats2half2_rn(f0.x*s, f1.x*s); u.h[1] = __floats2half2_rn(f2.x*s, 0.f);
    o0.x = u.i2.x; o0.y = u.i2.y;
    u.h[0] = __floats2half2_rn(f0.y*s, f1.y*s); u.h[1] = __floats2half2_rn(f2.y*s, 0.f);
    o0.z = u.i2.x; o0.w = u.i2.y;
    u.h[0] = __floats2half2_rn(f0.z*s, f1.z*s); u.h[1] = __floats2half2_rn(f2.z*s, 0.f);
    o1.x = u.i2.x; o1.y = u.i2.y;
    u.h[0] = __floats2half2_rn(f0.w*s, f1.w*s); u.h[1] = __floats2half2_rn(f2.w*s, 0.f);
    o1.z = u.i2.x; o1.w = u.i2.y;
    int4* out = reinterpret_cast<int4*>(packed) + (((size_t)b * DHW + v0) >> 1);
    out[0] = o0;
    out[1] = o1;
}

static __device__ __forceinline__ float2 h2f(unsigned u) {
    return __half22float2(__builtin_bit_cast(__half2, u));
}

// 8 lanes per point — one corner per lane. Refill = ONE 8-B load per lane
// (depth 1, all 8 corners in parallel). Border lanes load the clamped voxel
// and get weight 0 (fw/fh/fd == 0 there) — no edge logic needed.
// Trilinear = sum over lanes of corner * (wsel?fw:1-fw)(hsel?fh:1-fh)(dsel?fd:1-fd),
// reduced with a 3-round xor-butterfly (exact expansion of the nested lerp).
__global__ __launch_bounds__(256) void deform8_kernel(
    const float* __restrict__ verts,
    const float* __restrict__ affine,
    const __half* __restrict__ packed,
    const float* __restrict__ invaff,
    float* __restrict__ out_pred,
    float* __restrict__ out_flow,
    int N, int B) {
    long t = (long)blockIdx.x * blockDim.x + threadIdx.x;
    long total = (long)B * N;
    long pt = t >> 3;
    int sub = (int)(t & 7);
    bool valid = pt < total;
    long i = valid ? pt : total - 1;
    int b = (int)(i / N);
    int n = (int)(i - (long)b * N);
    int wsel = sub & 1;
    int hsel = (sub >> 1) & 1;
    int dsel = (sub >> 2) & 1;

    const float* A = affine + b * 16;
    const float* v = verts + (size_t)i * 3;
    float vx = v[0], vy = v[1], vz = v[2];
    float x = A[0] * vx + A[1] * vy + A[2]  * vz + A[3];
    float y = A[4] * vx + A[5] * vy + A[6]  * vz + A[7];
    float z = A[8] * vx + A[9] * vy + A[10] * vz + A[11];
    const float px = x, py = y, pz = z;

    const char* Pb = (const char*)(packed + (size_t)b * DHW * 4);

    float c0 = 0.f, c1 = 0.f, c2 = 0.f;   // own corner's 3 channels (pre-scaled)
    int key = -1;

    for (int s = 0; s < NSTEPS; s++) {
        float pd = fminf(fmaxf(x, 0.0f), (float)(DIM - 1));
        float ph = fminf(fmaxf(y, 0.0f), (float)(DIM - 1));
        float pw = fminf(fmaxf(z, 0.0f), (float)(DIM - 1));
        float fd0 = floorf(pd), fh0 = floorf(ph), fw0 = floorf(pw);
        int d0 = (int)fd0, h0 = (int)fh0, w0 = (int)fw0;
        float fd = pd - fd0, fh = ph - fh0, fw = pw - fw0;

        int k = (d0 * DIM + h0) * DIM + w0;
        if (k != key) {            // group-uniform: positions identical in group
            key = k;
            int dr = dsel ? min(d0 + 1, DIM - 1) : d0;
            int hr = hsel ? min(h0 + 1, DIM - 1) : h0;
            int wr = wsel ? min(w0 + 1, DIM - 1) : w0;
            uint2 q = *reinterpret_cast<const uint2*>(
                Pb + (size_t)((dr * DIM + hr) * DIM + wr) * 8);
            float2 q01 = h2f(q.x), q2_ = h2f(q.y);
            c0 = q01.x; c1 = q01.y; c2 = q2_.x;
        }

        float ww = wsel ? fw : 1.0f - fw;
        float wh = hsel ? fh : 1.0f - fh;
        float wd = dsel ? fd : 1.0f - fd;
        float w = ww * wh * wd;
        float v0 = c0 * w, v1 = c1 * w, v2 = c2 * w;
        v0 += __shfl_xor(v0, 1, 64); v0 += __shfl_xor(v0, 2, 64); v0 += __shfl_xor(v0, 4, 64);
        v1 += __shfl_xor(v1, 1, 64); v1 += __shfl_xor(v1, 2, 64); v1 += __shfl_xor(v1, 4, 64);
        v2 += __shfl_xor(v2, 1, 64); v2 += __shfl_xor(v2, 2, 64); v2 += __shfl_xor(v2, 4, 64);
        x += v0; y += v1; z += v2;
    }

    if (valid && sub < 3) {        // lane sub writes channel sub
        float posc = (sub == 0) ? x : (sub == 1) ? y : z;
        float p0c  = (sub == 0) ? px : (sub == 1) ? py : pz;
        float fint = posc - p0c;
        const float* Ai = invaff + b * 16 + sub * 4;
        float o = Ai[0] * x + Ai[1] * y + Ai[2] * z + Ai[3];
        out_pred[(size_t)i * 3 + sub] = o;                        // (B,N,3)
        out_flow[(size_t)b * 3 * N + (size_t)sub * N + n] = fint; // (B,3,N)
    }
}

// Fallback: f32 direct-gather (3 lanes/point) if ws can't hold the packed volume.
__global__ __launch_bounds__(256) void deform_kernel(
    const float* __restrict__ verts,
    const float* __restrict__ affine,
    const float* __restrict__ flow,
    const float* __restrict__ invaff,
    float* __restrict__ out_pred,
    float* __restrict__ out_flow,
    int N, int B) {
    int lane = threadIdx.x & 63;
    int wib  = threadIdx.x >> 6;
    long gwave = (long)blockIdx.x * (blockDim.x >> 6) + wib;
    int piw = lane / 3;
    if (piw > PTS_PER_WAVE - 1) piw = PTS_PER_WAVE - 1;
    int ch = lane - piw * 3;
    if (ch > 2) ch = 2;
    long pt = gwave * PTS_PER_WAVE + piw;
    bool valid = (lane < 63) && (pt < (long)B * N);
    long ptc = valid ? pt : ((long)B * N - 1);
    int b = (int)(ptc / N);
    int n = (int)(ptc - (long)b * N);
    const float* A = affine + b * 16;
    const float* v = verts + (size_t)ptc * 3;
    float vx = v[0], vy = v[1], vz = v[2];
    float x = A[0] * vx + A[1] * vy + A[2]  * vz + A[3];
    float y = A[4] * vx + A[5] * vy + A[6]  * vz + A[7];
    float z = A[8] * vx + A[9] * vy + A[10] * vz + A[11];
    float p0 = (ch == 0) ? x : (ch == 1) ? y : z;
    const float* Fc = flow + ((size_t)b * 3 + ch) * (size_t)DHW;
    const float scale = (float)(1.0 / NSTEPS);
    float cc[8];
    int key = -1;
    int bl = piw * 3;
    for (int s = 0; s < NSTEPS; s++) {
        float pd = fminf(fmaxf(x, 0.0f), (float)(DIM - 1));
        float ph = fminf(fmaxf(y, 0.0f), (float)(DIM - 1));
        float pw = fminf(fmaxf(z, 0.0f), (float)(DIM - 1));
        float fd0 = floorf(pd), fh0 = floorf(ph), fw0 = floorf(pw);
        int d0 = (int)fd0, h0 = (int)fh0, w0 = (int)fw0;
        float fd = pd - fd0, fh = ph - fh0, fw = pw - fw0;
        int k = (d0 * DIM + h0) * DIM + w0;
        if (k != key) {
            key = k;
            int d1 = min(d0 + 1, DIM - 1);
            int h1 = min(h0 + 1, DIM - 1);
            int w1 = min(w0 + 1, DIM - 1);
            int r00 = (d0 * DIM + h0) * DIM;
            int r01 = (d0 * DIM + h1) * DIM;
            int r10 = (d1 * DIM + h0) * DIM;
            int r11 = (d1 * DIM + h1) * DIM;
            cc[0] = Fc[r00 + w0] * scale;
            cc[1] = Fc[r00 + w1] * scale;
            cc[2] = Fc[r01 + w0] * scale;
            cc[3] = Fc[r01 + w1] * scale;
            cc[4] = Fc[r10 + w0] * scale;
            cc[5] = Fc[r10 + w1] * scale;
            cc[6] = Fc[r11 + w0] * scale;
            cc[7] = Fc[r11 + w1] * scale;
        }
        float omfw = 1.0f - fw, omfh = 1.0f - fh, omfd = 1.0f - fd;
        float c00 = cc[0] * omfw + cc[1] * fw;
        float c01 = cc[2] * omfw + cc[3] * fw;
        float c10 = cc[4] * omfw + cc[5] * fw;
        float c11 = cc[6] * omfw + cc[7] * fw;
        float c0 = c00 * omfh + c01 * fh;
        float c1 = c10 * omfh + c11 * fh;
        float val = c0 * omfd + c1 * fd;
        float v0 = __shfl(val, bl,     64);
        float v1 = __shfl(val, bl + 1, 64);
        float v2 = __shfl(val, bl + 2, 64);
        x += v0; y += v1; z += v2;
    }
    if (valid) {
        float posc = (ch == 0) ? x : (ch == 1) ? y : z;
        float fint = posc - p0;
        const float* Ai = invaff + b * 16 + ch * 4;
        float o = Ai[0] * x + Ai[1] * y + Ai[2] * z + Ai[3];
        out_pred[(size_t)ptc * 3 + ch] = o;
        out_flow[(size_t)b * 3 * N + (size_t)ch * N + n] = fint;
    }
}

extern "C" void kernel_launch(void* const* d_in, const int* in_sizes, int n_in,
                              void* d_out, int out_size, void* d_ws, size_t ws_size,
                              hipStream_t stream) {
    const float* verts  = (const float*)d_in[0];
    const float* affine = (const float*)d_in[1];
    const float* flow   = (const float*)d_in[2];

    int B = in_sizes[1] / 16;          // affine is B*4*4
    int N = in_sizes[0] / (3 * B);     // verts is B*N*3
    long total = (long)B * N;

    float* out_pred = (float*)d_out;                      // (B,N,3)
    float* out_flow = out_pred + (size_t)B * N * 3;       // (B,3,N)

    size_t packed_bytes = (size_t)B * DHW * 4 * sizeof(__half);  // 8B/voxel
    bool use_packed = (ws_size >= packed_bytes + 256);

    if (use_packed) {
        __half* packed = (__half*)d_ws;
        float* invaff  = (float*)((char*)d_ws + packed_bytes);
        hipLaunchKernelGGL(invert4x4_kernel, dim3(1), dim3(64), 0, stream,
                           affine, invaff, B);
        long quads = (DHW + 3) / 4;
        long vblocks = (quads + 255) / 256;
        hipLaunchKernelGGL(repack4_kernel, dim3((unsigned)vblocks, B), dim3(256), 0,
                           stream, flow, packed);
        long threads = total * 8;
        long blocks = (threads + 255) / 256;
        hipLaunchKernelGGL(deform8_kernel, dim3((unsigned)blocks), dim3(256), 0,
                           stream, verts, affine, packed, invaff,
                           out_pred, out_flow, N, B);
    } else {
        float* invaff = (float*)d_ws;
        hipLaunchKernelGGL(invert4x4_kernel, dim3(1), dim3(64), 0, stream,
                           affine, invaff, B);
        long waves  = (total + PTS_PER_WAVE - 1) / PTS_PER_WAVE;
        long blocks = (waves + 3) / 4;
        hipLaunchKernelGGL(deform_kernel, dim3((unsigned)blocks), dim3(256), 0,
                           stream, verts, affine, flow, invaff,
                           out_pred, out_flow, N, B);
    }
}